// Round 3
// baseline (312.067 us; speedup 1.0000x reference)
//
#include <hip/hip_runtime.h>
#include <hip/hip_bf16.h>

#define NIMG 256
#define CIN  256
#define PIX  784
#define DD   64
#define NP   200
#define NPP  208   // prototypes padded to 13*16
#define NCLS 10

#define XS 264     // row stride (bf16) xlds/w1lds: 132 dw; quad = (row + ...) & 7 rotation
#define HS 72      // row stride (bf16) htile/ftile/w2lds

typedef __attribute__((ext_vector_type(8))) short bf16x8;
typedef __attribute__((ext_vector_type(4))) float f32x4;
typedef __attribute__((ext_vector_type(4))) unsigned int u32x4;
typedef __attribute__((ext_vector_type(2))) unsigned int u32x2;

__device__ __forceinline__ unsigned short f2bf(float f) {
    union { float f; unsigned int u; } v; v.f = f;
    unsigned int r = v.u + 0x7fffu + ((v.u >> 16) & 1u);   // RNE
    return (unsigned short)(r >> 16);
}
__device__ __forceinline__ unsigned int pk2(float a, float b) {
    __hip_bfloat162 p = __float22bfloat162_rn(make_float2(a, b));
    return *(unsigned int*)&p;
}

#define MFMA(a, b, c) __builtin_amdgcn_mfma_f32_16x16x32_bf16((a), (b), (c), 0, 0, 0)

// LDS-only barrier (R1): all cross-wave deps are through LDS; keeps global
// prefetch loads in flight across barriers.
#define BARL() asm volatile("s_waitcnt lgkmcnt(0)\n\ts_barrier" ::: "memory")

__global__ __launch_bounds__(512, 2)
void proto_fused_kernel(const float* __restrict__ x,
                        const float* __restrict__ W1, const float* __restrict__ b1,
                        const float* __restrict__ W2, const float* __restrict__ b2,
                        const float* __restrict__ proto,
                        const float* __restrict__ lastW, const float* __restrict__ lastb,
                        float* __restrict__ out)
{
    // R2: xlds holds a 128-px stage (2 compute sub-tiles). HBM reads per
    // channel become 512 B contiguous runs (was 256 B) -> DRAM row locality.
    // (R3 = R2 resubmit: R2 bench was an infra failure, no data; kernel
    //  re-audited for OOB/hang -> clean.)
    __shared__ __align__(16) unsigned short xlds[128 * XS];     // 67.6 KB, [px][c]
    __shared__ __align__(16) unsigned short w1lds[64 * XS];     // 33.8 KB, [o][c]
    __shared__ __align__(16) unsigned short w2lds[64 * HS];     //  9.2 KB, [o][c]
    __shared__ __align__(16) unsigned short htile[64 * HS];     //  9.2 KB, [px][d]
    __shared__ __align__(16) unsigned short ftile[64 * HS];     //  9.2 KB, [px][d]
    __shared__ float p2lds[NPP];
    __shared__ float s2lds[2][64];      // per-half partial sums of f^2
    __shared__ float b1lds[DD], b2lds[DD];
    __shared__ unsigned int bmin[NPP];

    const int n    = blockIdx.x;
    const int t    = threadIdx.x;
    const int lane = t & 63;
    const int q    = lane >> 4;     // quad row within wave
    const int l15  = lane & 15;
    const int wave = t >> 6;
    const int s    = wave & 3;      // pixel strip (16 px) within 64-px sub-tile
    const int dh   = wave >> 2;     // half of the d/proto tiles this wave owns
    const int dt0  = dh * 2, dt1 = dh * 2 + 1;

    // ---- x load lane map: p4=((t>>2)&15)*4, c8grp=(t&3)|(wave<<2) ----
    const int p4   = ((t >> 2) & 15) * 4;
    const int c8i  = (t & 3) | ((t >> 6) << 2);  // 0..31
    const int c8   = c8i * 8;
    const float* xn = x + (size_t)n * CIN * PIX;

    // 16 float4 in flight = one 128-px stage. Per channel j the two
    // 64-px halves are issued back-to-back -> 512 B contiguous DRAM runs.
    float4 pf[16];
    auto load_tile128 = [&](int h) {
        const int px0 = h * 128;
        #pragma unroll
        for (int j = 0; j < 8; ++j) {
            #pragma unroll
            for (int half = 0; half < 2; ++half) {
                const int base = px0 + half * 64 + p4;
                const float* src = xn + (size_t)(c8 + j) * PIX + base;
                float4 v;
                if (base + 3 < PIX) {
                    v = *(const float4*)src;
                } else {
                    v.x = (base + 0 < PIX) ? src[0] : 0.f;
                    v.y = (base + 1 < PIX) ? src[1] : 0.f;
                    v.z = (base + 2 < PIX) ? src[2] : 0.f;
                    v.w = (base + 3 < PIX) ? src[3] : 0.f;
                }
                pf[j * 2 + half] = v;
            }
        }
    };
    auto store_tile128 = [&]() {   // register transpose -> 8x ds_write_b128
        #pragma unroll
        for (int half = 0; half < 2; ++half) {
            #pragma unroll
            for (int r = 0; r < 4; ++r) {
                u32x4 uv;
                uv.x = pk2(((const float*)&pf[0 + half])[r], ((const float*)&pf[2 + half])[r]);
                uv.y = pk2(((const float*)&pf[4 + half])[r], ((const float*)&pf[6 + half])[r]);
                uv.z = pk2(((const float*)&pf[8 + half])[r], ((const float*)&pf[10 + half])[r]);
                uv.w = pk2(((const float*)&pf[12 + half])[r], ((const float*)&pf[14 + half])[r]);
                *(u32x4*)&xlds[(half * 64 + p4 + r) * XS + c8] = uv;
            }
        }
    };

    // issue stage-0 HBM loads immediately; latency hides under weight staging
    load_tile128(0);

    // ---------------- one-time staging (vectorized) ----------------
    {   // W1: 64x256 fp32 = 4096 float4; 8 per thread
        const float4* W1v = (const float4*)W1;
        #pragma unroll
        for (int i = 0; i < 8; ++i) {
            int j = t + i * 512;
            float4 v = W1v[j];
            u32x2 w;
            w.x = pk2(v.x, v.y); w.y = pk2(v.z, v.w);
            *(u32x2*)&w1lds[(j >> 6) * XS + (j & 63) * 4] = w;
        }
    }
    {   // W2: 64x64 fp32 = 1024 float4; 2 per thread
        const float4* W2v = (const float4*)W2;
        #pragma unroll
        for (int i = 0; i < 2; ++i) {
            int j = t + i * 512;
            float4 v = W2v[j];
            u32x2 w;
            w.x = pk2(v.x, v.y); w.y = pk2(v.z, v.w);
            *(u32x2*)&w2lds[(j >> 4) * HS + (j & 15) * 4] = w;
        }
    }
    if (t < DD) { b1lds[t] = b1[t]; b2lds[t] = b2[t]; }
    if (t < NPP) {
        float acc = 0.f;
        if (t < NP) {
            const float4* pp = (const float4*)(proto + t * DD);
            #pragma unroll
            for (int i = 0; i < 16; ++i) {
                float4 v = pp[i];
                acc += v.x * v.x + v.y * v.y + v.z * v.z + v.w * v.w;
            }
        }
        p2lds[t] = acc;
        bmin[t] = 0x7f800000u;   // +inf bits (dist >= 0: uint order == float order)
    }

    // ---- prototype B-fragments: straight from global into registers ----
    bf16x8 pb0[7], pb1[7];
    #pragma unroll
    for (int it = 0; it < 7; ++it) {
        int pt = dh + 2 * it;
        int p  = pt * 16 + l15;
        int pr = (p < NP) ? p : (NP - 1);        // clamp pads (results discarded)
        const float4* src = (const float4*)(proto + (size_t)pr * DD + q * 8);
        float4 a = src[0], b = src[1];           // k = q*8 .. q*8+7
        float4 c = src[8], d = src[9];           // k = 32 + q*8 ..
        union { u32x4 u; bf16x8 h; } cv0, cv1;
        cv0.u.x = pk2(a.x, a.y); cv0.u.y = pk2(a.z, a.w);
        cv0.u.z = pk2(b.x, b.y); cv0.u.w = pk2(b.z, b.w);
        cv1.u.x = pk2(c.x, c.y); cv1.u.y = pk2(c.z, c.w);
        cv1.u.z = pk2(d.x, d.y); cv1.u.w = pk2(d.z, d.w);
        pb0[it] = cv0.h; pb1[it] = cv1.h;
    }

    // prologue: stage 0 into xlds, stage 1 in flight in pf
    store_tile128();
    load_tile128(1);
    BARL();                      // stage-1 loads stay in flight across this

    // ---- hoist W2 B-fragments + p2 into registers ----
    // (W1 fragments NOT hoisted -> re-read from w1lds each P1; frees 64 VGPRs
    //  for the 16-float4 pf. Bank pattern: 2-way on b128 = free.)
    bf16x8 w2f0[2], w2f1[2];
    #pragma unroll
    for (int kk = 0; kk < 2; ++kk) {
        w2f0[kk] = *(const bf16x8*)&w2lds[(dt0 * 16 + l15) * HS + kk * 32 + q * 8];
        w2f1[kk] = *(const bf16x8*)&w2lds[(dt1 * 16 + l15) * HS + kk * 32 + q * 8];
    }
    float p2r[7];
    #pragma unroll
    for (int it = 0; it < 7; ++it) {
        int pidx = (dh + 2 * it) * 16 + l15;
        p2r[it] = p2lds[pidx < NPP ? pidx : (NPP - 1)];
    }

    float rmin[7];
    #pragma unroll
    for (int it = 0; it < 7; ++it) rmin[it] = 1e30f;

    const int w1r0 = (dt0 * 16 + l15) * XS + q * 8;
    const int w1r1 = (dt1 * 16 + l15) * XS + q * 8;

    // ------------- main loop: 13 sub-tiles (64 px), staging every odd st -------------
    for (int st = 0; st < 13; ++st) {
        const int px0   = st * 64;
        const int rbase = (st & 1) * 64;     // which half of the staged 128-px buffer

        // ---- P1: GEMM1 (reads xlds + w1lds) -> htile ----
        {
            f32x4 acc0 = {0.f, 0.f, 0.f, 0.f}, acc1 = {0.f, 0.f, 0.f, 0.f};
            const int arow = (rbase + s * 16 + l15) * XS + q * 8;
            #pragma unroll
            for (int kk = 0; kk < 8; ++kk) {
                bf16x8 a  = *(const bf16x8*)&xlds[arow + kk * 32];
                bf16x8 w0 = *(const bf16x8*)&w1lds[w1r0 + kk * 32];
                bf16x8 w1v = *(const bf16x8*)&w1lds[w1r1 + kk * 32];
                acc0 = MFMA(a, w0, acc0);
                acc1 = MFMA(a, w1v, acc1);
            }
            #pragma unroll
            for (int r = 0; r < 4; ++r) {
                int prow = s * 16 + q * 4 + r;
                float h0 = fmaxf(acc0[r] + b1lds[dt0 * 16 + l15], 0.f);
                float h1 = fmaxf(acc1[r] + b1lds[dt1 * 16 + l15], 0.f);
                htile[prow * HS + dt0 * 16 + l15] = f2bf(h0);
                htile[prow * HS + dt1 * 16 + l15] = f2bf(h1);
            }
        }
        BARL();   // htile visibility; x prefetch (vmcnt) NOT drained

        // ---- P2: (odd st) stage next 128-px buffer + prefetch; GEMM2 -> ftile, s2 ----
        if (st & 1) {
            store_tile128();                       // buffer (st>>1)+1; waits vmcnt here
            if (st <= 9) load_tile128((st >> 1) + 2);
        }
        {
            f32x4 acc0 = {0.f, 0.f, 0.f, 0.f}, acc1 = {0.f, 0.f, 0.f, 0.f};
            const int arowH = (s * 16 + l15) * HS + q * 8;
            bf16x8 a0 = *(const bf16x8*)&htile[arowH];
            bf16x8 a1 = *(const bf16x8*)&htile[arowH + 32];
            acc0 = MFMA(a0, w2f0[0], acc0);
            acc0 = MFMA(a1, w2f0[1], acc0);
            acc1 = MFMA(a0, w2f1[0], acc1);
            acc1 = MFMA(a1, w2f1[1], acc1);
            #pragma unroll
            for (int r = 0; r < 4; ++r) {
                int prow = s * 16 + q * 4 + r;
                float z0 = acc0[r] + b2lds[dt0 * 16 + l15];
                float z1 = acc1[r] + b2lds[dt1 * 16 + l15];
                float f0 = __builtin_amdgcn_rcpf(1.0f + __builtin_amdgcn_exp2f(z0 * -1.44269504f));
                float f1 = __builtin_amdgcn_rcpf(1.0f + __builtin_amdgcn_exp2f(z1 * -1.44269504f));
                ftile[prow * HS + dt0 * 16 + l15] = f2bf(f0);
                ftile[prow * HS + dt1 * 16 + l15] = f2bf(f1);
                float v = f0 * f0 + f1 * f1;
                v += __shfl_xor(v, 1, 64);
                v += __shfl_xor(v, 2, 64);
                v += __shfl_xor(v, 4, 64);
                v += __shfl_xor(v, 8, 64);
                if (l15 == 0)
                    s2lds[dh][prow] = (px0 + prow < PIX) ? v : 1e30f;  // pad poison
            }
        }
        BARL();   // ftile/s2lds/xlds visibility; prefetch loads stay in flight

        // ---- P3: GEMM3 distances -> per-lane running min (regs only) ----
        {
            const int arowF = (s * 16 + l15) * HS + q * 8;
            bf16x8 a0 = *(const bf16x8*)&ftile[arowF];
            bf16x8 a1 = *(const bf16x8*)&ftile[arowF + 32];
            float s2v[4];
            #pragma unroll
            for (int r = 0; r < 4; ++r) {
                int pl = s * 16 + q * 4 + r;
                s2v[r] = s2lds[0][pl] + s2lds[1][pl];
            }
            #pragma unroll
            for (int it = 0; it < 7; ++it) {
                f32x4 acc = {0.f, 0.f, 0.f, 0.f};
                acc = MFMA(a0, pb0[it], acc);
                acc = MFMA(a1, pb1[it], acc);
                float m = 1e30f;
                #pragma unroll
                for (int r = 0; r < 4; ++r) {
                    float dist = fmaxf(s2v[r] - 2.f * acc[r] + p2r[it], 0.f);
                    m = fminf(m, dist);
                }
                rmin[it] = fminf(rmin[it], m);
            }
        }
        // no barrier: next P1 reads xlds (written pre-P2-barrier) + w1lds (const),
        // writes htile (last read pre-P2-barrier); P3 touched neither.
    }

    // ---- final min reduction: regs -> bmin ----
    #pragma unroll
    for (int it = 0; it < 7; ++it) {
        int pt = dh + 2 * it;
        if (pt < 13) {
            float m = rmin[it];
            m = fminf(m, __shfl_xor(m, 16, 64));
            m = fminf(m, __shfl_xor(m, 32, 64));
            if (lane < 16) atomicMin(&bmin[pt * 16 + l15], __float_as_uint(m));
        }
    }
    BARL();   // ds_atomic visibility (lgkmcnt covers LDS atomics)

    // ---------------- epilogue: min_distances + logits ----------------
    if (t < NP) {
        out[NIMG * NCLS + (size_t)n * NP + t] = __uint_as_float(bmin[t]);
    }
    if (t < 320) {
        int c = t >> 5, j = t & 31;
        float acc = 0.f;
        for (int p = j; p < NP; p += 32)
            acc += __uint_as_float(bmin[p]) * lastW[c * NP + p];
        acc += __shfl_xor(acc, 1, 32);
        acc += __shfl_xor(acc, 2, 32);
        acc += __shfl_xor(acc, 4, 32);
        acc += __shfl_xor(acc, 8, 32);
        acc += __shfl_xor(acc, 16, 32);
        if (j == 0) out[(size_t)n * NCLS + c] = -acc + lastb[c];
    }
}

extern "C" void kernel_launch(void* const* d_in, const int* in_sizes, int n_in,
                              void* d_out, int out_size, void* d_ws, size_t ws_size,
                              hipStream_t stream) {
    const float* x     = (const float*)d_in[0];
    const float* W1    = (const float*)d_in[1];
    const float* b1    = (const float*)d_in[2];
    const float* W2    = (const float*)d_in[3];
    const float* b2    = (const float*)d_in[4];
    const float* proto = (const float*)d_in[5];
    const float* lastW = (const float*)d_in[6];
    const float* lastb = (const float*)d_in[7];
    float* out = (float*)d_out;

    proto_fused_kernel<<<dim3(NIMG), dim3(512), 0, stream>>>(
        x, W1, b1, W2, b2, proto, lastW, lastb, out);
}